// Round 16
// baseline (4311.505 us; speedup 1.0000x reference)
//
#include <hip/hip_runtime.h>
#include <hip/hip_bf16.h>
#include <cstdint>
#include <cstddef>

#define NDIMC   128
#define DEPTHC  6
#define NPASSESC 4
#define NNODES  50000
#define NEDGES  800000
#define NODEIN  5
#define LNEPS   1e-5f

// ---------------------------------------------------------------------------
// ws layout (bytes) — ~224 MiB, below proven-safe 256,000,004
#define H_OFF    0ull                     // h:  50000*128*4  = 25.6 MB fp32
#define E_OFF    25600000ull              // e:  800000*128*2 = 204.8 MB bf16 (CSR-slot order)
#define PW_OFF   230400000ull             // packed weights: 4 * 196,608 B bf16
#define FLAG_OFF 231186432ull
#define DEG_OFF  231186436ull             // 50001 int
#define RS_OFF   231386440ull             // rowstart: 50001 int
#define CUR_OFF  231586444ull             // cursor:   50000 int
#define EIDX_OFF 231786444ull             // eidx:     800000 int -> ends 234,986,444
#define PWMAT    98304                    // shorts per packed matrix (6*2*8192)

typedef __attribute__((ext_vector_type(8))) short mgn_sh8;
typedef __attribute__((ext_vector_type(4))) float mgn_f32x4;

// ---------------------------------------------------------------------------
__device__ __forceinline__ unsigned mgn_bf16bits(float f) {
    unsigned x = __float_as_uint(f);
    return (x + 0x7fffu + ((x >> 16) & 1u)) >> 16;   // RNE
}
__device__ __forceinline__ unsigned mgn_pk(float a, float b) {
    __hip_bfloat162 t = __float22bfloat162_rn(make_float2(a, b));
    union { __hip_bfloat162 h; unsigned u; } c; c.h = t; return c.u;
}

// async 16B global->LDS DMA (no VGPR round-trip; tracked by vmcnt)
__device__ __forceinline__ void mgn_cp16(const unsigned short* g, unsigned short* l) {
    __builtin_amdgcn_global_load_lds(
        (const __attribute__((address_space(1))) void*)g,
        (__attribute__((address_space(3))) void*)l, 16, 0, 0);
}
// Stage one 16 KB K-half (8192 shorts = 16 chunks of 512) with BW waves.
// One chunk per global_load_lds (64 lanes x 16 B). Per-wave count = 16/BW.
// r15 BUG: wrote 32/BW chunks -> 2x buffer overrun -> corrupted wb1/xl.
template <int BW>
__device__ __forceinline__ void mgn_stage_half(const unsigned short* __restrict__ src,
                                               unsigned short* wbuf, int tid) {
    const int w = tid >> 6, l = tid & 63;
#pragma unroll
    for (int i = 0; i < 16 / BW; ++i) {
        const int off = (w * (16 / BW) + i) * 512 + l * 8;   // shorts
        mgn_cp16(src + off, wbuf + off);
    }
}

// ---------------------------------------------------------------------------
// flag = 1 -> ij is int32, flag = 0 -> ij is int64
__global__ void mgn_detect_kernel(const int* __restrict__ ij, int* __restrict__ flag) {
    __shared__ int any;
    if (threadIdx.x == 0) any = 0;
    __syncthreads();
    if (ij[2 * threadIdx.x + 1] != 0) atomicOr(&any, 1);
    __syncthreads();
    if (threadIdx.x == 0) *flag = any;
}

__device__ __forceinline__ long mgn_load_idx(const int* __restrict__ ij, long pos, int is32) {
    if (is32) return (long)ij[pos];
    const long long* ij8 = (const long long*)ij;
    return (long)ij8[pos];
}

// ---------------------------------------------------------------------------
// Pack fp32 row-major W[d][k][n] into half-major MFMA B-frag order:
// i = ((((d*2+sh)*8+t)*2+sp)*64+lane)*8+j holds
//   W[d][(sh*2+sp)*32 + (lane>>4)*8 + j][(lane&15)*8 + t]
// so K-half sh is a contiguous 16 KB block; lane owns 8 consecutive out cols.
__global__ void mgn_pack_kernel(const float* __restrict__ W, unsigned short* __restrict__ pw) {
    int i = blockIdx.x * blockDim.x + threadIdx.x;
    if (i >= PWMAT) return;
    int j    = i & 7;
    int lane = (i >> 3) & 63;
    int sp   = (i >> 9) & 1;
    int t    = (i >> 10) & 7;
    int sh   = (i >> 13) & 1;
    int d    = i >> 14;
    int k = (sh * 2 + sp) * 32 + (lane >> 4) * 8 + j;
    int n = (lane & 15) * 8 + t;
    pw[i] = (unsigned short)mgn_bf16bits(W[(d * NDIMC + k) * NDIMC + n]);
}

// ---------------------------------------------------------------------------
// CSR build: histogram -> scan -> fill
__global__ void mgn_deg_kernel(const int* __restrict__ ij, const int* __restrict__ flag,
                               int* __restrict__ deg) {
    int e = blockIdx.x * blockDim.x + threadIdx.x;
    if (e >= NEDGES) return;
    int dst = (int)mgn_load_idx(ij, (long)NEDGES + e, *flag);
    atomicAdd(&deg[dst], 1);
}

__global__ void mgn_scan_kernel(const int* __restrict__ deg,
                                int* __restrict__ rowstart, int* __restrict__ cursor) {
    __shared__ int partial[256];
    const int tid = threadIdx.x;
    const int CH = (NNODES + 255) / 256;   // 196
    const int base = tid * CH;
    int s = 0;
    for (int i = 0; i < CH; ++i) {
        int idx = base + i;
        if (idx < NNODES) s += deg[idx];
    }
    partial[tid] = s;
    __syncthreads();
    for (int off = 1; off < 256; off <<= 1) {
        int add = (tid >= off) ? partial[tid - off] : 0;
        __syncthreads();
        partial[tid] += add;
        __syncthreads();
    }
    int run = (tid == 0) ? 0 : partial[tid - 1];
    for (int i = 0; i < CH; ++i) {
        int idx = base + i;
        if (idx < NNODES) {
            rowstart[idx] = run;
            cursor[idx]   = run;
            run += deg[idx];
        }
    }
    if (tid == 255) rowstart[NNODES] = run;
}

__global__ void mgn_fill_kernel(const int* __restrict__ ij, const int* __restrict__ flag,
                                int* __restrict__ cursor, int* __restrict__ eidx) {
    int e = blockIdx.x * blockDim.x + threadIdx.x;
    if (e >= NEDGES) return;
    int dst = (int)mgn_load_idx(ij, (long)NEDGES + e, *flag);
    int pos = atomicAdd(&cursor[dst], 1);
    eidx[pos] = e;
}

// ---------------------------------------------------------------------------
__global__ void mgn_encoder_kernel(const float* __restrict__ v,
                                   const float* __restrict__ encW,
                                   const float* __restrict__ encB,
                                   float* __restrict__ h) {
    int idx = blockIdx.x * blockDim.x + threadIdx.x;
    if (idx >= NNODES * NDIMC) return;
    int n = idx >> 7, d = idx & 127;
    float acc = encB[d];
#pragma unroll
    for (int k = 0; k < NODEIN; ++k)
        acc = fmaf(v[n * NODEIN + k], encW[k * NDIMC + d], acc);
    h[idx] = acc;
}

__global__ void mgn_decoder_kernel(const float* __restrict__ h,
                                   const float* __restrict__ decW,
                                   const float* __restrict__ decB,
                                   float* __restrict__ out) {
    int idx = blockIdx.x * blockDim.x + threadIdx.x;
    if (idx >= NNODES * NODEIN) return;
    int n = idx / NODEIN, j = idx % NODEIN;
    float acc = decB[j];
#pragma unroll 8
    for (int k = 0; k < NDIMC; ++k)
        acc = fmaf(h[n * NDIMC + k], decW[k * NODEIN + j], acc);
    out[idx] = acc;
}

// ---------------------------------------------------------------------------
// Fused 6-deep residual MLP, bf16 MFMA core, fp32 residual/LN.
// r14 structure + BW-wave blocks. Edge: BW=8 (512 thr, 128 rows) — one
// wbuf ping-pong serves 8 waves: W-DMA and barriers per row halve, LDS
// 66.8 KB -> 2 blocks/CU = 16 waves/CU (up from 12). Node: BW=4 (proven).
// e lives in CSR-SLOT order (edge slot gr = edge eidx[gr]); node aggregation
// reads Eb[rs..re] contiguously. LN is single-pass (sum/sumsq via
// independent shfl chains) with folded coefficients.
// Schedule per depth (4 barriers):
//   stage W1h1->buf1 | GEMM1h0(buf0)          | barrier
//   stage W2h0->buf0 | GEMM1h1(buf1) + h1-epi | barrier
//   stage W2h1->buf1 | GEMM2h0(buf0)          | barrier
//   stage W1'h0->buf0| GEMM2h1(buf1) + LN-epi | barrier
template <int MODE, int BW>
__global__ __launch_bounds__(BW * 64, 2) void mgn_mlp6_mfma_kernel(
    float* __restrict__ Xf,               // node: h
    unsigned short* __restrict__ Eb,      // e buffer (CSR-slot order)
    const float* __restrict__ H,          // edge: h for gather
    const int* __restrict__ ij,
    const int* __restrict__ flag,
    const int* __restrict__ rowstart,     // node CSR
    const int* __restrict__ eidx,         // edge: slot -> original edge id
    int addE, int nrows,
    const unsigned short* __restrict__ PW1,
    const unsigned short* __restrict__ PW2,
    const float* __restrict__ B1, const float* __restrict__ B2,
    const float* __restrict__ G,  const float* __restrict__ BT)
{
    __shared__ unsigned short xl[BW * 16 * 136];   // x/h1 tile, row stride 136
    __shared__ unsigned short wb0[8192];           // W K-half ping (16 KB)
    __shared__ unsigned short wb1[8192];           // W K-half pong (16 KB)
    const int tid = threadIdx.x;
    const int w   = tid >> 6;
    const int l   = tid & 63;
    const int q   = l >> 4;
    const int lm  = l & 15;
    const int ct  = lm * 8;                        // first of lane's 8 cols
    const int wbase = w * 16;                      // wave's first local row
    const long rowbase = (long)blockIdx.x * (16 * BW);

    const int is32 = (MODE == 1) ? *flag : 0;

    // pre-stage W1[0]h0 -> buf0 (drains at first __syncthreads)
    mgn_stage_half<BW>(PW1, wb0, tid);

    // ---- tile load: xres fp32 regs (C layout) + LDS bf16 (A source)
    float xres[4][8];
#pragma unroll
    for (int r = 0; r < 4; ++r) {
        const int rloc = wbase + q * 4 + r;
        long gr = rowbase + rloc;
        bool ok = gr < nrows;
        float xv[8];
#pragma unroll
        for (int t = 0; t < 8; ++t) xv[t] = 0.f;
        if (MODE == 1) {
            if (ok) {
                long er = (long)eidx[gr];     // original edge id for this slot
                long i0 = mgn_load_idx(ij, er, is32);
                long i1 = mgn_load_idx(ij, (long)NEDGES + er, is32);
                const float* p0 = H + i0 * NDIMC + ct;
                const float* p1 = H + i1 * NDIMC + ct;
                float4 a0 = *(const float4*)p0, a1 = *(const float4*)(p0 + 4);
                float4 b0 = *(const float4*)p1, b1 = *(const float4*)(p1 + 4);
                xv[0] = a0.x - b0.x; xv[1] = a0.y - b0.y;
                xv[2] = a0.z - b0.z; xv[3] = a0.w - b0.w;
                xv[4] = a1.x - b1.x; xv[5] = a1.y - b1.y;
                xv[6] = a1.z - b1.z; xv[7] = a1.w - b1.w;
                if (addE) {
                    uint4 u4 = *(const uint4*)(Eb + (size_t)gr * NDIMC + ct);
                    xv[0] += __uint_as_float(u4.x << 16);
                    xv[1] += __uint_as_float(u4.x & 0xffff0000u);
                    xv[2] += __uint_as_float(u4.y << 16);
                    xv[3] += __uint_as_float(u4.y & 0xffff0000u);
                    xv[4] += __uint_as_float(u4.z << 16);
                    xv[5] += __uint_as_float(u4.z & 0xffff0000u);
                    xv[6] += __uint_as_float(u4.w << 16);
                    xv[7] += __uint_as_float(u4.w & 0xffff0000u);
                }
            }
        } else {
            if (ok) {
                float4 a0 = *(const float4*)(Xf + gr * NDIMC + ct);
                float4 a1 = *(const float4*)(Xf + gr * NDIMC + ct + 4);
                xv[0] = a0.x; xv[1] = a0.y; xv[2] = a0.z; xv[3] = a0.w;
                xv[4] = a1.x; xv[5] = a1.y; xv[6] = a1.z; xv[7] = a1.w;
                // CSR aggregate: CONTIGUOUS slot range (no indirection)
                int rs = rowstart[gr], re = rowstart[gr + 1];
                for (int k = rs; k < re; ++k) {
                    uint4 u4 = *(const uint4*)(Eb + (size_t)k * NDIMC + ct);
                    xv[0] += __uint_as_float(u4.x << 16);
                    xv[1] += __uint_as_float(u4.x & 0xffff0000u);
                    xv[2] += __uint_as_float(u4.y << 16);
                    xv[3] += __uint_as_float(u4.y & 0xffff0000u);
                    xv[4] += __uint_as_float(u4.z << 16);
                    xv[5] += __uint_as_float(u4.z & 0xffff0000u);
                    xv[6] += __uint_as_float(u4.w << 16);
                    xv[7] += __uint_as_float(u4.w & 0xffff0000u);
                }
            }
        }
#pragma unroll
        for (int t = 0; t < 8; ++t) xres[r][t] = xv[t];
        uint4 pk;
        pk.x = mgn_pk(xv[0], xv[1]); pk.y = mgn_pk(xv[2], xv[3]);
        pk.z = mgn_pk(xv[4], xv[5]); pk.w = mgn_pk(xv[6], xv[7]);
        *(uint4*)&xl[rloc * 136 + ct] = pk;
    }

    __syncthreads();   // W1[0]h0 visible in buf0

    mgn_sh8 a[4];
    mgn_f32x4 acc[8];
    const int arow = (wbase + lm) * 136;

    for (int d = 0; d < DEPTHC; ++d) {
        const unsigned short* pw1 = PW1 + (size_t)(d * 2) * 8192;
        const unsigned short* pw2 = PW2 + (size_t)(d * 2) * 8192;

        // ---- step 1: stage W1h1->buf1 | GEMM1h0 from buf0
        mgn_stage_half<BW>(pw1 + 8192, wb1, tid);

        float4 b1a = *(const float4*)(B1 + d * NDIMC + ct);
        float4 b1b = *(const float4*)(B1 + d * NDIMC + ct + 4);
        float b1v[8] = {b1a.x, b1a.y, b1a.z, b1a.w, b1b.x, b1b.y, b1b.z, b1b.w};

#pragma unroll
        for (int s = 0; s < 4; ++s)
            a[s] = *(const mgn_sh8*)&xl[arow + s * 32 + q * 8];
        // bias pre-loaded into accumulator (saves the epilogue adds)
#pragma unroll
        for (int t = 0; t < 8; ++t)
            acc[t] = (mgn_f32x4){b1v[t], b1v[t], b1v[t], b1v[t]};
#pragma unroll
        for (int t = 0; t < 8; ++t)
#pragma unroll
            for (int sp = 0; sp < 2; ++sp) {
                mgn_sh8 b = *(const mgn_sh8*)&wb0[(t * 2 + sp) * 512 + l * 8];
                acc[t] = __builtin_amdgcn_mfma_f32_16x16x32_bf16(a[sp], b, acc[t], 0, 0, 0);
            }
        __syncthreads();   // buf1 (W1h1) visible; all waves done with buf0

        // ---- step 2: stage W2h0->buf0 | GEMM1h1 from buf1 + h1 epilogue
        mgn_stage_half<BW>(pw2, wb0, tid);
#pragma unroll
        for (int t = 0; t < 8; ++t)
#pragma unroll
            for (int sp = 0; sp < 2; ++sp) {
                mgn_sh8 b = *(const mgn_sh8*)&wb1[(t * 2 + sp) * 512 + l * 8];
                acc[t] = __builtin_amdgcn_mfma_f32_16x16x32_bf16(a[2 + sp], b, acc[t], 0, 0, 0);
            }
#pragma unroll
        for (int r = 0; r < 4; ++r) {
            const int rloc = wbase + q * 4 + r;
            float h1[8];
#pragma unroll
            for (int t = 0; t < 8; ++t) h1[t] = fmaxf(acc[t][r], 0.f);
            uint4 pk;
            pk.x = mgn_pk(h1[0], h1[1]); pk.y = mgn_pk(h1[2], h1[3]);
            pk.z = mgn_pk(h1[4], h1[5]); pk.w = mgn_pk(h1[6], h1[7]);
            *(uint4*)&xl[rloc * 136 + ct] = pk;
        }
        __syncthreads();   // buf0 (W2h0) visible; all waves done with buf1

        // ---- step 3: stage W2h1->buf1 | GEMM2h0 from buf0
        mgn_stage_half<BW>(pw2 + 8192, wb1, tid);

        float4 b2a = *(const float4*)(B2 + d * NDIMC + ct);
        float4 b2b = *(const float4*)(B2 + d * NDIMC + ct + 4);
        float4 ga  = *(const float4*)(G  + d * NDIMC + ct);
        float4 gb  = *(const float4*)(G  + d * NDIMC + ct + 4);
        float4 bta = *(const float4*)(BT + d * NDIMC + ct);
        float4 btb = *(const float4*)(BT + d * NDIMC + ct + 4);
        float b2v[8] = {b2a.x, b2a.y, b2a.z, b2a.w, b2b.x, b2b.y, b2b.z, b2b.w};
        float gv[8]  = {ga.x, ga.y, ga.z, ga.w, gb.x, gb.y, gb.z, gb.w};
        float btv[8] = {bta.x, bta.y, bta.z, bta.w, btb.x, btb.y, btb.z, btb.w};

#pragma unroll
        for (int s = 0; s < 4; ++s)
            a[s] = *(const mgn_sh8*)&xl[arow + s * 32 + q * 8];
#pragma unroll
        for (int t = 0; t < 8; ++t)
            acc[t] = (mgn_f32x4){b2v[t], b2v[t], b2v[t], b2v[t]};
#pragma unroll
        for (int t = 0; t < 8; ++t)
#pragma unroll
            for (int sp = 0; sp < 2; ++sp) {
                mgn_sh8 b = *(const mgn_sh8*)&wb0[(t * 2 + sp) * 512 + l * 8];
                acc[t] = __builtin_amdgcn_mfma_f32_16x16x32_bf16(a[sp], b, acc[t], 0, 0, 0);
            }
        __syncthreads();   // buf1 (W2h1) visible; all waves done with buf0

        // ---- step 4: stage W1[d+1]h0->buf0 | GEMM2h1 from buf1 + LN epilogue
        if (d + 1 < DEPTHC)
            mgn_stage_half<BW>(PW1 + (size_t)((d + 1) * 2) * 8192, wb0, tid);
#pragma unroll
        for (int t = 0; t < 8; ++t)
#pragma unroll
            for (int sp = 0; sp < 2; ++sp) {
                mgn_sh8 b = *(const mgn_sh8*)&wb1[(t * 2 + sp) * 512 + l * 8];
                acc[t] = __builtin_amdgcn_mfma_f32_16x16x32_bf16(a[2 + sp], b, acc[t], 0, 0, 0);
            }
#pragma unroll
        for (int r = 0; r < 4; ++r) {
            const int rloc = wbase + q * 4 + r;
            float h2[8];
#pragma unroll
            for (int t = 0; t < 8; ++t) h2[t] = fmaxf(acc[t][r], 0.f);
            // single-pass sum & sumsq; independent shfl chains overlap
            float sum = 0.f, ssq = 0.f;
#pragma unroll
            for (int t = 0; t < 8; ++t) {
                sum += h2[t];
                ssq = fmaf(h2[t], h2[t], ssq);
            }
            sum += __shfl_xor(sum, 1); ssq += __shfl_xor(ssq, 1);
            sum += __shfl_xor(sum, 2); ssq += __shfl_xor(ssq, 2);
            sum += __shfl_xor(sum, 4); ssq += __shfl_xor(ssq, 4);
            sum += __shfl_xor(sum, 8); ssq += __shfl_xor(ssq, 8);
            float mean = sum * 0.0078125f;
            float var  = fmaf(-mean, mean, ssq * 0.0078125f);
            float rstd = rsqrtf(var + LNEPS);
#pragma unroll
            for (int t = 0; t < 8; ++t) {
                float at = rstd * gv[t];
                float ctt = fmaf(-mean, at, btv[t]);
                xres[r][t] += fmaf(h2[t], at, ctt);
            }
            if (d != DEPTHC - 1) {
                uint4 pk;
                pk.x = mgn_pk(xres[r][0], xres[r][1]);
                pk.y = mgn_pk(xres[r][2], xres[r][3]);
                pk.z = mgn_pk(xres[r][4], xres[r][5]);
                pk.w = mgn_pk(xres[r][6], xres[r][7]);
                *(uint4*)&xl[rloc * 136 + ct] = pk;
            }
        }
        if (d + 1 < DEPTHC) __syncthreads();   // buf0 (W1') visible; buf1 free
    }

    // ---- tile store
#pragma unroll
    for (int r = 0; r < 4; ++r) {
        const int rloc = wbase + q * 4 + r;
        long gr = rowbase + rloc;
        if (gr < nrows) {
            if (MODE == 1) {
                uint4 pk;
                pk.x = mgn_pk(xres[r][0], xres[r][1]);
                pk.y = mgn_pk(xres[r][2], xres[r][3]);
                pk.z = mgn_pk(xres[r][4], xres[r][5]);
                pk.w = mgn_pk(xres[r][6], xres[r][7]);
                *(uint4*)(Eb + (size_t)gr * NDIMC + ct) = pk;
            } else {
                float4 a0 = {xres[r][0], xres[r][1], xres[r][2], xres[r][3]};
                float4 a1 = {xres[r][4], xres[r][5], xres[r][6], xres[r][7]};
                *(float4*)(Xf + gr * NDIMC + ct)     = a0;
                *(float4*)(Xf + gr * NDIMC + ct + 4) = a1;
            }
        }
    }
}

// ---------------------------------------------------------------------------
extern "C" void kernel_launch(void* const* d_in, const int* in_sizes, int n_in,
                              void* d_out, int out_size, void* d_ws, size_t ws_size,
                              hipStream_t stream) {
    const float* v    = (const float*)d_in[0];
    const int*   ij   = (const int*)d_in[1];
    const float* encW = (const float*)d_in[2];
    const float* encB = (const float*)d_in[3];
    const float* eW1  = (const float*)d_in[4];
    const float* eB1  = (const float*)d_in[5];
    const float* eW2  = (const float*)d_in[6];
    const float* eB2  = (const float*)d_in[7];
    const float* eG   = (const float*)d_in[8];
    const float* eBT  = (const float*)d_in[9];
    const float* nW1  = (const float*)d_in[10];
    const float* nB1  = (const float*)d_in[11];
    const float* nW2  = (const float*)d_in[12];
    const float* nB2  = (const float*)d_in[13];
    const float* nG   = (const float*)d_in[14];
    const float* nBT  = (const float*)d_in[15];
    const float* decW = (const float*)d_in[16];
    const float* decB = (const float*)d_in[17];
    float* out = (float*)d_out;

    char* ws = (char*)d_ws;
    float*          h    = (float*)(ws + H_OFF);
    unsigned short* ebuf = (unsigned short*)(ws + E_OFF);
    unsigned short* pw   = (unsigned short*)(ws + PW_OFF);
    int*            flag = (int*)(ws + FLAG_OFF);
    int*            deg  = (int*)(ws + DEG_OFF);
    int*            rstt = (int*)(ws + RS_OFF);
    int*            curs = (int*)(ws + CUR_OFF);
    int*            eidx = (int*)(ws + EIDX_OFF);

    mgn_detect_kernel<<<1, 256, 0, stream>>>(ij, flag);
    mgn_pack_kernel<<<(PWMAT + 255) / 256, 256, 0, stream>>>(eW1, pw + 0 * PWMAT);
    mgn_pack_kernel<<<(PWMAT + 255) / 256, 256, 0, stream>>>(eW2, pw + 1 * PWMAT);
    mgn_pack_kernel<<<(PWMAT + 255) / 256, 256, 0, stream>>>(nW1, pw + 2 * PWMAT);
    mgn_pack_kernel<<<(PWMAT + 255) / 256, 256, 0, stream>>>(nW2, pw + 3 * PWMAT);

    // CSR build (static graph; rebuilt every call for graph-capture safety)
    hipMemsetAsync(deg, 0, (size_t)(NNODES + 1) * sizeof(int), stream);
    mgn_deg_kernel<<<(NEDGES + 255) / 256, 256, 0, stream>>>(ij, flag, deg);
    mgn_scan_kernel<<<1, 256, 0, stream>>>(deg, rstt, curs);
    mgn_fill_kernel<<<(NEDGES + 255) / 256, 256, 0, stream>>>(ij, flag, curs, eidx);

    mgn_encoder_kernel<<<(NNODES * NDIMC + 255) / 256, 256, 0, stream>>>(v, encW, encB, h);

    for (int p = 0; p < NPASSESC; ++p) {
        // edge MLP (fused gather; e in CSR-slot order; BW=8 -> 128 rows/block)
        mgn_mlp6_mfma_kernel<1, 8><<<NEDGES / 128, 512, 0, stream>>>(
            nullptr, ebuf, h, ij, flag, nullptr, eidx, p > 0 ? 1 : 0, NEDGES,
            pw + 0 * PWMAT, pw + 1 * PWMAT, eB1, eB2, eG, eBT);
        // node MLP with fused CSR aggregation (contiguous Eb reads; BW=4)
        mgn_mlp6_mfma_kernel<0, 4><<<(NNODES + 63) / 64, 256, 0, stream>>>(
            h, ebuf, nullptr, nullptr, nullptr, rstt, nullptr, 0, NNODES,
            pw + 2 * PWMAT, pw + 3 * PWMAT, nB1, nB2, nG, nBT);
    }

    mgn_decoder_kernel<<<(NNODES * NODEIN + 255) / 256, 256, 0, stream>>>(h, decW, decB, out);
}

// Round 17
// 3315.443 us; speedup vs baseline: 1.3004x; 1.3004x over previous
//
#include <hip/hip_runtime.h>
#include <hip/hip_bf16.h>
#include <cstdint>
#include <cstddef>

#define NDIMC   128
#define DEPTHC  6
#define NPASSESC 4
#define NNODES  50000
#define NEDGES  800000
#define NODEIN  5
#define LNEPS   1e-5f

// ---------------------------------------------------------------------------
// ws layout (bytes) — ~224 MiB, below proven-safe 256,000,004
#define H_OFF    0ull                     // h:  50000*128*4  = 25.6 MB fp32
#define E_OFF    25600000ull              // e:  800000*128*2 = 204.8 MB bf16 (CSR-slot order)
#define PW_OFF   230400000ull             // packed weights: 4 * 196,608 B bf16
#define FLAG_OFF 231186432ull
#define DEG_OFF  231186436ull             // 50001 int
#define RS_OFF   231386440ull             // rowstart: 50001 int
#define CUR_OFF  231586444ull             // cursor:   50000 int
#define EIDX_OFF 231786444ull             // eidx:     800000 int -> ends 234,986,444
#define PWMAT    98304                    // shorts per packed matrix (6*2*8192)

typedef __attribute__((ext_vector_type(8))) short mgn_sh8;
typedef __attribute__((ext_vector_type(4))) float mgn_f32x4;

// ---------------------------------------------------------------------------
__device__ __forceinline__ unsigned mgn_bf16bits(float f) {
    unsigned x = __float_as_uint(f);
    return (x + 0x7fffu + ((x >> 16) & 1u)) >> 16;   // RNE
}
__device__ __forceinline__ unsigned mgn_pk(float a, float b) {
    __hip_bfloat162 t = __float22bfloat162_rn(make_float2(a, b));
    union { __hip_bfloat162 h; unsigned u; } c; c.h = t; return c.u;
}

// async 16B global->LDS DMA (no VGPR round-trip; tracked by vmcnt)
__device__ __forceinline__ void mgn_cp16(const unsigned short* g, unsigned short* l) {
    __builtin_amdgcn_global_load_lds(
        (const __attribute__((address_space(1))) void*)g,
        (__attribute__((address_space(3))) void*)l, 16, 0, 0);
}
// Stage one 16 KB K-half (8192 shorts = 16 chunks of 512) with BW waves.
// One chunk per global_load_lds (64 lanes x 16 B). Per-wave count = 16/BW.
template <int BW>
__device__ __forceinline__ void mgn_stage_half(const unsigned short* __restrict__ src,
                                               unsigned short* wbuf, int tid) {
    const int w = tid >> 6, l = tid & 63;
#pragma unroll
    for (int i = 0; i < 16 / BW; ++i) {
        const int off = (w * (16 / BW) + i) * 512 + l * 8;   // shorts
        mgn_cp16(src + off, wbuf + off);
    }
}

// ---------------------------------------------------------------------------
// flag = 1 -> ij is int32, flag = 0 -> ij is int64
__global__ void mgn_detect_kernel(const int* __restrict__ ij, int* __restrict__ flag) {
    __shared__ int any;
    if (threadIdx.x == 0) any = 0;
    __syncthreads();
    if (ij[2 * threadIdx.x + 1] != 0) atomicOr(&any, 1);
    __syncthreads();
    if (threadIdx.x == 0) *flag = any;
}

__device__ __forceinline__ long mgn_load_idx(const int* __restrict__ ij, long pos, int is32) {
    if (is32) return (long)ij[pos];
    const long long* ij8 = (const long long*)ij;
    return (long)ij8[pos];
}

// ---------------------------------------------------------------------------
// Pack fp32 row-major W[d][k][n] into half-major MFMA B-frag order:
// i = ((((d*2+sh)*8+t)*2+sp)*64+lane)*8+j holds
//   W[d][(sh*2+sp)*32 + (lane>>4)*8 + j][(lane&15)*8 + t]
// so K-half sh is a contiguous 16 KB block; lane owns 8 consecutive out cols.
__global__ void mgn_pack_kernel(const float* __restrict__ W, unsigned short* __restrict__ pw) {
    int i = blockIdx.x * blockDim.x + threadIdx.x;
    if (i >= PWMAT) return;
    int j    = i & 7;
    int lane = (i >> 3) & 63;
    int sp   = (i >> 9) & 1;
    int t    = (i >> 10) & 7;
    int sh   = (i >> 13) & 1;
    int d    = i >> 14;
    int k = (sh * 2 + sp) * 32 + (lane >> 4) * 8 + j;
    int n = (lane & 15) * 8 + t;
    pw[i] = (unsigned short)mgn_bf16bits(W[(d * NDIMC + k) * NDIMC + n]);
}

// ---------------------------------------------------------------------------
// CSR build: histogram -> scan -> fill
__global__ void mgn_deg_kernel(const int* __restrict__ ij, const int* __restrict__ flag,
                               int* __restrict__ deg) {
    int e = blockIdx.x * blockDim.x + threadIdx.x;
    if (e >= NEDGES) return;
    int dst = (int)mgn_load_idx(ij, (long)NEDGES + e, *flag);
    atomicAdd(&deg[dst], 1);
}

__global__ void mgn_scan_kernel(const int* __restrict__ deg,
                                int* __restrict__ rowstart, int* __restrict__ cursor) {
    __shared__ int partial[256];
    const int tid = threadIdx.x;
    const int CH = (NNODES + 255) / 256;   // 196
    const int base = tid * CH;
    int s = 0;
    for (int i = 0; i < CH; ++i) {
        int idx = base + i;
        if (idx < NNODES) s += deg[idx];
    }
    partial[tid] = s;
    __syncthreads();
    for (int off = 1; off < 256; off <<= 1) {
        int add = (tid >= off) ? partial[tid - off] : 0;
        __syncthreads();
        partial[tid] += add;
        __syncthreads();
    }
    int run = (tid == 0) ? 0 : partial[tid - 1];
    for (int i = 0; i < CH; ++i) {
        int idx = base + i;
        if (idx < NNODES) {
            rowstart[idx] = run;
            cursor[idx]   = run;
            run += deg[idx];
        }
    }
    if (tid == 255) rowstart[NNODES] = run;
}

__global__ void mgn_fill_kernel(const int* __restrict__ ij, const int* __restrict__ flag,
                                int* __restrict__ cursor, int* __restrict__ eidx) {
    int e = blockIdx.x * blockDim.x + threadIdx.x;
    if (e >= NEDGES) return;
    int dst = (int)mgn_load_idx(ij, (long)NEDGES + e, *flag);
    int pos = atomicAdd(&cursor[dst], 1);
    eidx[pos] = e;
}

// ---------------------------------------------------------------------------
__global__ void mgn_encoder_kernel(const float* __restrict__ v,
                                   const float* __restrict__ encW,
                                   const float* __restrict__ encB,
                                   float* __restrict__ h) {
    int idx = blockIdx.x * blockDim.x + threadIdx.x;
    if (idx >= NNODES * NDIMC) return;
    int n = idx >> 7, d = idx & 127;
    float acc = encB[d];
#pragma unroll
    for (int k = 0; k < NODEIN; ++k)
        acc = fmaf(v[n * NODEIN + k], encW[k * NDIMC + d], acc);
    h[idx] = acc;
}

__global__ void mgn_decoder_kernel(const float* __restrict__ h,
                                   const float* __restrict__ decW,
                                   const float* __restrict__ decB,
                                   float* __restrict__ out) {
    int idx = blockIdx.x * blockDim.x + threadIdx.x;
    if (idx >= NNODES * NODEIN) return;
    int n = idx / NODEIN, j = idx % NODEIN;
    float acc = decB[j];
#pragma unroll 8
    for (int k = 0; k < NDIMC; ++k)
        acc = fmaf(h[n * NDIMC + k], decW[k * NODEIN + j], acc);
    out[idx] = acc;
}

// ---------------------------------------------------------------------------
// Fused 6-deep residual MLP, bf16 MFMA core, fp32 residual/LN.
// FINAL config = r14 (best measured): BW=4 (256 thr, 64 rows/block),
// half-stage (16 KB) ping-pong W staging, 50.2 KB LDS -> 3 blocks/CU.
// r16 showed BW=8 (16 phase-locked waves, 2 blocks) is WORSE than 12 waves
// in 3 independently-phased blocks — cross-block phase diversity beats raw
// occupancy. e lives in CSR-slot order; node aggregation reads Eb[rs..re]
// contiguously. LN single-pass (sum/sumsq, folded coefficients).
// Schedule per depth (4 barriers):
//   stage W1h1->buf1 | GEMM1h0(buf0)          | barrier
//   stage W2h0->buf0 | GEMM1h1(buf1) + h1-epi | barrier
//   stage W2h1->buf1 | GEMM2h0(buf0)          | barrier
//   stage W1'h0->buf0| GEMM2h1(buf1) + LN-epi | barrier
template <int MODE, int BW>
__global__ __launch_bounds__(BW * 64, 2) void mgn_mlp6_mfma_kernel(
    float* __restrict__ Xf,               // node: h
    unsigned short* __restrict__ Eb,      // e buffer (CSR-slot order)
    const float* __restrict__ H,          // edge: h for gather
    const int* __restrict__ ij,
    const int* __restrict__ flag,
    const int* __restrict__ rowstart,     // node CSR
    const int* __restrict__ eidx,         // edge: slot -> original edge id
    int addE, int nrows,
    const unsigned short* __restrict__ PW1,
    const unsigned short* __restrict__ PW2,
    const float* __restrict__ B1, const float* __restrict__ B2,
    const float* __restrict__ G,  const float* __restrict__ BT)
{
    __shared__ unsigned short xl[BW * 16 * 136];   // x/h1 tile, row stride 136
    __shared__ unsigned short wb0[8192];           // W K-half ping (16 KB)
    __shared__ unsigned short wb1[8192];           // W K-half pong (16 KB)
    const int tid = threadIdx.x;
    const int w   = tid >> 6;
    const int l   = tid & 63;
    const int q   = l >> 4;
    const int lm  = l & 15;
    const int ct  = lm * 8;                        // first of lane's 8 cols
    const int wbase = w * 16;                      // wave's first local row
    const long rowbase = (long)blockIdx.x * (16 * BW);

    const int is32 = (MODE == 1) ? *flag : 0;

    // pre-stage W1[0]h0 -> buf0 (drains at first __syncthreads)
    mgn_stage_half<BW>(PW1, wb0, tid);

    // ---- tile load: xres fp32 regs (C layout) + LDS bf16 (A source)
    float xres[4][8];
#pragma unroll
    for (int r = 0; r < 4; ++r) {
        const int rloc = wbase + q * 4 + r;
        long gr = rowbase + rloc;
        bool ok = gr < nrows;
        float xv[8];
#pragma unroll
        for (int t = 0; t < 8; ++t) xv[t] = 0.f;
        if (MODE == 1) {
            if (ok) {
                long er = (long)eidx[gr];     // original edge id for this slot
                long i0 = mgn_load_idx(ij, er, is32);
                long i1 = mgn_load_idx(ij, (long)NEDGES + er, is32);
                const float* p0 = H + i0 * NDIMC + ct;
                const float* p1 = H + i1 * NDIMC + ct;
                float4 a0 = *(const float4*)p0, a1 = *(const float4*)(p0 + 4);
                float4 b0 = *(const float4*)p1, b1 = *(const float4*)(p1 + 4);
                xv[0] = a0.x - b0.x; xv[1] = a0.y - b0.y;
                xv[2] = a0.z - b0.z; xv[3] = a0.w - b0.w;
                xv[4] = a1.x - b1.x; xv[5] = a1.y - b1.y;
                xv[6] = a1.z - b1.z; xv[7] = a1.w - b1.w;
                if (addE) {
                    uint4 u4 = *(const uint4*)(Eb + (size_t)gr * NDIMC + ct);
                    xv[0] += __uint_as_float(u4.x << 16);
                    xv[1] += __uint_as_float(u4.x & 0xffff0000u);
                    xv[2] += __uint_as_float(u4.y << 16);
                    xv[3] += __uint_as_float(u4.y & 0xffff0000u);
                    xv[4] += __uint_as_float(u4.z << 16);
                    xv[5] += __uint_as_float(u4.z & 0xffff0000u);
                    xv[6] += __uint_as_float(u4.w << 16);
                    xv[7] += __uint_as_float(u4.w & 0xffff0000u);
                }
            }
        } else {
            if (ok) {
                float4 a0 = *(const float4*)(Xf + gr * NDIMC + ct);
                float4 a1 = *(const float4*)(Xf + gr * NDIMC + ct + 4);
                xv[0] = a0.x; xv[1] = a0.y; xv[2] = a0.z; xv[3] = a0.w;
                xv[4] = a1.x; xv[5] = a1.y; xv[6] = a1.z; xv[7] = a1.w;
                // CSR aggregate: CONTIGUOUS slot range (no indirection)
                int rs = rowstart[gr], re = rowstart[gr + 1];
                for (int k = rs; k < re; ++k) {
                    uint4 u4 = *(const uint4*)(Eb + (size_t)k * NDIMC + ct);
                    xv[0] += __uint_as_float(u4.x << 16);
                    xv[1] += __uint_as_float(u4.x & 0xffff0000u);
                    xv[2] += __uint_as_float(u4.y << 16);
                    xv[3] += __uint_as_float(u4.y & 0xffff0000u);
                    xv[4] += __uint_as_float(u4.z << 16);
                    xv[5] += __uint_as_float(u4.z & 0xffff0000u);
                    xv[6] += __uint_as_float(u4.w << 16);
                    xv[7] += __uint_as_float(u4.w & 0xffff0000u);
                }
            }
        }
#pragma unroll
        for (int t = 0; t < 8; ++t) xres[r][t] = xv[t];
        uint4 pk;
        pk.x = mgn_pk(xv[0], xv[1]); pk.y = mgn_pk(xv[2], xv[3]);
        pk.z = mgn_pk(xv[4], xv[5]); pk.w = mgn_pk(xv[6], xv[7]);
        *(uint4*)&xl[rloc * 136 + ct] = pk;
    }

    __syncthreads();   // W1[0]h0 visible in buf0

    mgn_sh8 a[4];
    mgn_f32x4 acc[8];
    const int arow = (wbase + lm) * 136;

    for (int d = 0; d < DEPTHC; ++d) {
        const unsigned short* pw1 = PW1 + (size_t)(d * 2) * 8192;
        const unsigned short* pw2 = PW2 + (size_t)(d * 2) * 8192;

        // ---- step 1: stage W1h1->buf1 | GEMM1h0 from buf0
        mgn_stage_half<BW>(pw1 + 8192, wb1, tid);

        float4 b1a = *(const float4*)(B1 + d * NDIMC + ct);
        float4 b1b = *(const float4*)(B1 + d * NDIMC + ct + 4);
        float b1v[8] = {b1a.x, b1a.y, b1a.z, b1a.w, b1b.x, b1b.y, b1b.z, b1b.w};

#pragma unroll
        for (int s = 0; s < 4; ++s)
            a[s] = *(const mgn_sh8*)&xl[arow + s * 32 + q * 8];
        // bias pre-loaded into accumulator (saves the epilogue adds)
#pragma unroll
        for (int t = 0; t < 8; ++t)
            acc[t] = (mgn_f32x4){b1v[t], b1v[t], b1v[t], b1v[t]};
#pragma unroll
        for (int t = 0; t < 8; ++t)
#pragma unroll
            for (int sp = 0; sp < 2; ++sp) {
                mgn_sh8 b = *(const mgn_sh8*)&wb0[(t * 2 + sp) * 512 + l * 8];
                acc[t] = __builtin_amdgcn_mfma_f32_16x16x32_bf16(a[sp], b, acc[t], 0, 0, 0);
            }
        __syncthreads();   // buf1 (W1h1) visible; all waves done with buf0

        // ---- step 2: stage W2h0->buf0 | GEMM1h1 from buf1 + h1 epilogue
        mgn_stage_half<BW>(pw2, wb0, tid);
#pragma unroll
        for (int t = 0; t < 8; ++t)
#pragma unroll
            for (int sp = 0; sp < 2; ++sp) {
                mgn_sh8 b = *(const mgn_sh8*)&wb1[(t * 2 + sp) * 512 + l * 8];
                acc[t] = __builtin_amdgcn_mfma_f32_16x16x32_bf16(a[2 + sp], b, acc[t], 0, 0, 0);
            }
#pragma unroll
        for (int r = 0; r < 4; ++r) {
            const int rloc = wbase + q * 4 + r;
            float h1[8];
#pragma unroll
            for (int t = 0; t < 8; ++t) h1[t] = fmaxf(acc[t][r], 0.f);
            uint4 pk;
            pk.x = mgn_pk(h1[0], h1[1]); pk.y = mgn_pk(h1[2], h1[3]);
            pk.z = mgn_pk(h1[4], h1[5]); pk.w = mgn_pk(h1[6], h1[7]);
            *(uint4*)&xl[rloc * 136 + ct] = pk;
        }
        __syncthreads();   // buf0 (W2h0) visible; all waves done with buf1

        // ---- step 3: stage W2h1->buf1 | GEMM2h0 from buf0
        mgn_stage_half<BW>(pw2 + 8192, wb1, tid);

        float4 b2a = *(const float4*)(B2 + d * NDIMC + ct);
        float4 b2b = *(const float4*)(B2 + d * NDIMC + ct + 4);
        float4 ga  = *(const float4*)(G  + d * NDIMC + ct);
        float4 gb  = *(const float4*)(G  + d * NDIMC + ct + 4);
        float4 bta = *(const float4*)(BT + d * NDIMC + ct);
        float4 btb = *(const float4*)(BT + d * NDIMC + ct + 4);
        float b2v[8] = {b2a.x, b2a.y, b2a.z, b2a.w, b2b.x, b2b.y, b2b.z, b2b.w};
        float gv[8]  = {ga.x, ga.y, ga.z, ga.w, gb.x, gb.y, gb.z, gb.w};
        float btv[8] = {bta.x, bta.y, bta.z, bta.w, btb.x, btb.y, btb.z, btb.w};

#pragma unroll
        for (int s = 0; s < 4; ++s)
            a[s] = *(const mgn_sh8*)&xl[arow + s * 32 + q * 8];
#pragma unroll
        for (int t = 0; t < 8; ++t)
            acc[t] = (mgn_f32x4){b2v[t], b2v[t], b2v[t], b2v[t]};
#pragma unroll
        for (int t = 0; t < 8; ++t)
#pragma unroll
            for (int sp = 0; sp < 2; ++sp) {
                mgn_sh8 b = *(const mgn_sh8*)&wb0[(t * 2 + sp) * 512 + l * 8];
                acc[t] = __builtin_amdgcn_mfma_f32_16x16x32_bf16(a[sp], b, acc[t], 0, 0, 0);
            }
        __syncthreads();   // buf1 (W2h1) visible; all waves done with buf0

        // ---- step 4: stage W1[d+1]h0->buf0 | GEMM2h1 from buf1 + LN epilogue
        if (d + 1 < DEPTHC)
            mgn_stage_half<BW>(PW1 + (size_t)((d + 1) * 2) * 8192, wb0, tid);
#pragma unroll
        for (int t = 0; t < 8; ++t)
#pragma unroll
            for (int sp = 0; sp < 2; ++sp) {
                mgn_sh8 b = *(const mgn_sh8*)&wb1[(t * 2 + sp) * 512 + l * 8];
                acc[t] = __builtin_amdgcn_mfma_f32_16x16x32_bf16(a[2 + sp], b, acc[t], 0, 0, 0);
            }
#pragma unroll
        for (int r = 0; r < 4; ++r) {
            const int rloc = wbase + q * 4 + r;
            float h2[8];
#pragma unroll
            for (int t = 0; t < 8; ++t) h2[t] = fmaxf(acc[t][r], 0.f);
            // single-pass sum & sumsq; independent shfl chains overlap
            float sum = 0.f, ssq = 0.f;
#pragma unroll
            for (int t = 0; t < 8; ++t) {
                sum += h2[t];
                ssq = fmaf(h2[t], h2[t], ssq);
            }
            sum += __shfl_xor(sum, 1); ssq += __shfl_xor(ssq, 1);
            sum += __shfl_xor(sum, 2); ssq += __shfl_xor(ssq, 2);
            sum += __shfl_xor(sum, 4); ssq += __shfl_xor(ssq, 4);
            sum += __shfl_xor(sum, 8); ssq += __shfl_xor(ssq, 8);
            float mean = sum * 0.0078125f;
            float var  = fmaf(-mean, mean, ssq * 0.0078125f);
            float rstd = rsqrtf(var + LNEPS);
#pragma unroll
            for (int t = 0; t < 8; ++t) {
                float at = rstd * gv[t];
                float ctt = fmaf(-mean, at, btv[t]);
                xres[r][t] += fmaf(h2[t], at, ctt);
            }
            if (d != DEPTHC - 1) {
                uint4 pk;
                pk.x = mgn_pk(xres[r][0], xres[r][1]);
                pk.y = mgn_pk(xres[r][2], xres[r][3]);
                pk.z = mgn_pk(xres[r][4], xres[r][5]);
                pk.w = mgn_pk(xres[r][6], xres[r][7]);
                *(uint4*)&xl[rloc * 136 + ct] = pk;
            }
        }
        if (d + 1 < DEPTHC) __syncthreads();   // buf0 (W1') visible; buf1 free
    }

    // ---- tile store
#pragma unroll
    for (int r = 0; r < 4; ++r) {
        const int rloc = wbase + q * 4 + r;
        long gr = rowbase + rloc;
        if (gr < nrows) {
            if (MODE == 1) {
                uint4 pk;
                pk.x = mgn_pk(xres[r][0], xres[r][1]);
                pk.y = mgn_pk(xres[r][2], xres[r][3]);
                pk.z = mgn_pk(xres[r][4], xres[r][5]);
                pk.w = mgn_pk(xres[r][6], xres[r][7]);
                *(uint4*)(Eb + (size_t)gr * NDIMC + ct) = pk;
            } else {
                float4 a0 = {xres[r][0], xres[r][1], xres[r][2], xres[r][3]};
                float4 a1 = {xres[r][4], xres[r][5], xres[r][6], xres[r][7]};
                *(float4*)(Xf + gr * NDIMC + ct)     = a0;
                *(float4*)(Xf + gr * NDIMC + ct + 4) = a1;
            }
        }
    }
}

// ---------------------------------------------------------------------------
extern "C" void kernel_launch(void* const* d_in, const int* in_sizes, int n_in,
                              void* d_out, int out_size, void* d_ws, size_t ws_size,
                              hipStream_t stream) {
    const float* v    = (const float*)d_in[0];
    const int*   ij   = (const int*)d_in[1];
    const float* encW = (const float*)d_in[2];
    const float* encB = (const float*)d_in[3];
    const float* eW1  = (const float*)d_in[4];
    const float* eB1  = (const float*)d_in[5];
    const float* eW2  = (const float*)d_in[6];
    const float* eB2  = (const float*)d_in[7];
    const float* eG   = (const float*)d_in[8];
    const float* eBT  = (const float*)d_in[9];
    const float* nW1  = (const float*)d_in[10];
    const float* nB1  = (const float*)d_in[11];
    const float* nW2  = (const float*)d_in[12];
    const float* nB2  = (const float*)d_in[13];
    const float* nG   = (const float*)d_in[14];
    const float* nBT  = (const float*)d_in[15];
    const float* decW = (const float*)d_in[16];
    const float* decB = (const float*)d_in[17];
    float* out = (float*)d_out;

    char* ws = (char*)d_ws;
    float*          h    = (float*)(ws + H_OFF);
    unsigned short* ebuf = (unsigned short*)(ws + E_OFF);
    unsigned short* pw   = (unsigned short*)(ws + PW_OFF);
    int*            flag = (int*)(ws + FLAG_OFF);
    int*            deg  = (int*)(ws + DEG_OFF);
    int*            rstt = (int*)(ws + RS_OFF);
    int*            curs = (int*)(ws + CUR_OFF);
    int*            eidx = (int*)(ws + EIDX_OFF);

    mgn_detect_kernel<<<1, 256, 0, stream>>>(ij, flag);
    mgn_pack_kernel<<<(PWMAT + 255) / 256, 256, 0, stream>>>(eW1, pw + 0 * PWMAT);
    mgn_pack_kernel<<<(PWMAT + 255) / 256, 256, 0, stream>>>(eW2, pw + 1 * PWMAT);
    mgn_pack_kernel<<<(PWMAT + 255) / 256, 256, 0, stream>>>(nW1, pw + 2 * PWMAT);
    mgn_pack_kernel<<<(PWMAT + 255) / 256, 256, 0, stream>>>(nW2, pw + 3 * PWMAT);

    // CSR build (static graph; rebuilt every call for graph-capture safety)
    hipMemsetAsync(deg, 0, (size_t)(NNODES + 1) * sizeof(int), stream);
    mgn_deg_kernel<<<(NEDGES + 255) / 256, 256, 0, stream>>>(ij, flag, deg);
    mgn_scan_kernel<<<1, 256, 0, stream>>>(deg, rstt, curs);
    mgn_fill_kernel<<<(NEDGES + 255) / 256, 256, 0, stream>>>(ij, flag, curs, eidx);

    mgn_encoder_kernel<<<(NNODES * NDIMC + 255) / 256, 256, 0, stream>>>(v, encW, encB, h);

    for (int p = 0; p < NPASSESC; ++p) {
        // edge MLP (fused gather; e in CSR-slot order; BW=4 -> 64 rows/block)
        mgn_mlp6_mfma_kernel<1, 4><<<NEDGES / 64, 256, 0, stream>>>(
            nullptr, ebuf, h, ij, flag, nullptr, eidx, p > 0 ? 1 : 0, NEDGES,
            pw + 0 * PWMAT, pw + 1 * PWMAT, eB1, eB2, eG, eBT);
        // node MLP with fused CSR aggregation (contiguous Eb reads; BW=4)
        mgn_mlp6_mfma_kernel<0, 4><<<(NNODES + 63) / 64, 256, 0, stream>>>(
            h, ebuf, nullptr, nullptr, nullptr, rstt, nullptr, 0, NNODES,
            pw + 2 * PWMAT, pw + 3 * PWMAT, nB1, nB2, nG, nBT);
    }

    mgn_decoder_kernel<<<(NNODES * NODEIN + 255) / 256, 256, 0, stream>>>(h, decW, decB, out);
}